// Round 6
// baseline (114.555 us; speedup 1.0000x reference)
//
#include <hip/hip_runtime.h>

#define E_ 15000
#define D_ 200
#define L_ 64
#define B_ 256
#define LOG2E 1.4426950408889634f

typedef float v2f __attribute__((ext_vector_type(2)));

// ws layout (chunk-contiguous: chunk c = b's [16c, 16c+16)):
//   qtc @ 0      : [16][200][16] f32  qtc[c][d][bb] = emb_e[e1,d]*emb_rel[rel,d]
//   suc @ 204800 : [16][64][16]  f32  (lit[e1,l]-c[l])*r[l]
//   wtc @ 270336 : [16][64][16]  f32  nfw[rel,l]
//   r   @ 335872 : [64] f32           sqrt(log2e/var[l])
#define QTC_OFF 0
#define SUC_OFF 204800
#define WTC_OFF 270336
#define R_OFF   335872

__global__ __launch_bounds__(256) void setup_k(
    const float* __restrict__ emb_e, const float* __restrict__ emb_rel,
    const float* __restrict__ nfw,   const float* __restrict__ lit,
    const float* __restrict__ c,     const float* __restrict__ var,
    const int* __restrict__ e1,      const int* __restrict__ rel,
    float* __restrict__ qtc, float* __restrict__ suc,
    float* __restrict__ wtc, float* __restrict__ r)
{
    const int b = blockIdx.x;
    const int t = threadIdx.x;
    const int ie = e1[b];
    const int ir = rel[b];
    const int cb = (b >> 4);          // chunk
    const int bb = (b & 15);
    if (t < D_) qtc[cb * 3200 + t * 16 + bb] =
        emb_e[ie * D_ + t] * emb_rel[ir * D_ + t];
    if (t < L_) {
        const float rl = sqrtf(LOG2E / var[t]);
        suc[cb * 1024 + t * 16 + bb] = (lit[ie * L_ + t] - c[t]) * rl;
        wtc[cb * 1024 + t * 16 + bb] = nfw[ir * L_ + t];
        if (b == 0) r[t] = rl;
    }
}

// 1880 blocks = 235 e-strips x 4 y-groups x 2 half-groups; 256 thr = 4 waves.
// Wave s owns reduction slice d in [50s,50s+50), l in [16s,16s+16); each
// thread keeps its e-row slice in registers (loaded once). Per-chunk b-operands
// are staged coalesced into LDS; inner loop reads them at wave-uniform
// addresses (broadcast, conflict-free) -> zero VMEM in the hot loop.
__global__ __launch_bounds__(256, 4) void main_k(
    const float* __restrict__ emb_e, const float* __restrict__ lit,
    const float* __restrict__ qtc,   const float* __restrict__ suc,
    const float* __restrict__ wtc,   const float* __restrict__ r,
    float* __restrict__ out)
{
    __shared__ float qt_s[3200];        // 12.8 KB [d][16]
    __shared__ float su_s[1024];        //  4.0 KB [l][16]
    __shared__ float wt_s[1024];        //  4.0 KB [l][16]
    __shared__ float comb[4][16][64];   // 16.0 KB [split][bb][lane]

    // Bijective XCD swizzle: 1880 = 8*235. All 8 (y,h) siblings of an e-strip
    // are consecutive on one XCD -> e-row L2 reuse + store-line merging.
    const int w    = blockIdx.x;
    const int xcd  = w & 7;
    const int slot = w >> 3;
    const int orig = xcd * 235 + slot;
    const int x = orig >> 3;            // e-strip 0..234
    const int y = (orig >> 1) & 3;      // b-group 0..3
    const int h = orig & 1;             // half-group 0..1

    const int tid  = threadIdx.x;
    const int lane = tid & 63;
    const int s    = __builtin_amdgcn_readfirstlane(tid >> 6);
    const int e    = x * 64 + lane;
    const int ec   = (e < E_) ? e : (E_ - 1);
    const int d0   = s * 50;
    const int l0   = s * 16;

    // ---- one-time register-resident e-row slices ----
    float ee[50];
    {
        const float* ep = emb_e + (size_t)ec * D_ + d0;   // 8B aligned
        #pragma unroll
        for (int i = 0; i < 25; ++i) {
            const v2f v = *(const v2f*)(ep + 2 * i);
            ee[2 * i] = v.x; ee[2 * i + 1] = v.y;
        }
    }
    float u[16];                        // u[l] = lit*r
    {
        const float* lp = lit + (size_t)ec * L_ + l0;     // 16B aligned
        #pragma unroll
        for (int i = 0; i < 4; ++i) {
            const float4 v = *(const float4*)(lp + 4 * i);
            u[4*i]   = v.x * r[l0 + 4*i];
            u[4*i+1] = v.y * r[l0 + 4*i + 1];
            u[4*i+2] = v.z * r[l0 + 4*i + 2];
            u[4*i+3] = v.w * r[l0 + 4*i + 3];
        }
    }

    // ---- 2 chunks of 16 b's each ----
    #pragma unroll 1
    for (int cc = 0; cc < 2; ++cc) {
        const int cab = y * 4 + h * 2 + cc;   // absolute chunk 0..15
        const int b0  = cab * 16;

        // coalesced staging: 20.8 KB from L2 -> LDS
        {
            const float4* qsrc = (const float4*)(qtc + cab * 3200);
            float4*       qdst = (float4*)qt_s;
            #pragma unroll
            for (int i = 0; i < 3; ++i) qdst[tid + 256 * i] = qsrc[tid + 256 * i];
            if (tid < 32) qdst[768 + tid] = qsrc[768 + tid];
            ((float4*)su_s)[tid] = ((const float4*)(suc + cab * 1024))[tid];
            ((float4*)wt_s)[tid] = ((const float4*)(wtc + cab * 1024))[tid];
        }
        __syncthreads();

        v2f acc[8];
        #pragma unroll
        for (int j = 0; j < 8; ++j) acc[j] = (v2f)(0.0f);

        // structural: acc[bb] += ee[d] * qt_s[d0+d][bb]
        #pragma unroll
        for (int d = 0; d < 50; ++d) {
            const v2f* q2 = (const v2f*)(qt_s + (d0 + d) * 16);
            const v2f ev = {ee[d], ee[d]};
            #pragma unroll
            for (int j = 0; j < 8; ++j)
                acc[j] = __builtin_elementwise_fma(ev, q2[j], acc[j]);
        }

        // RBF: acc[bb] += exp2(-(su-u)^2) * wt
        #pragma unroll
        for (int l = 0; l < 16; ++l) {
            const v2f* s2 = (const v2f*)(su_s + (l0 + l) * 16);
            const v2f* w2 = (const v2f*)(wt_s + (l0 + l) * 16);
            const v2f uv = {u[l], u[l]};
            #pragma unroll
            for (int j = 0; j < 8; ++j) {
                const v2f t = s2[j] - uv;
                const v2f m = -(t * t);
                const v2f ph = {__builtin_amdgcn_exp2f(m.x),
                                __builtin_amdgcn_exp2f(m.y)};
                acc[j] = __builtin_elementwise_fma(ph, w2[j], acc[j]);
            }
        }

        // combine 4 reduction splits via LDS; wave s finalizes bb in [4s,4s+4)
        #pragma unroll
        for (int j = 0; j < 8; ++j) {
            comb[s][2 * j][lane]     = acc[j].x;
            comb[s][2 * j + 1][lane] = acc[j].y;
        }
        __syncthreads();
        if (e < E_) {
            #pragma unroll
            for (int bi = 0; bi < 4; ++bi) {
                const int bb = 4 * s + bi;
                const float z = comb[0][bb][lane] + comb[1][bb][lane]
                              + comb[2][bb][lane] + comb[3][bb][lane];
                const float ezn = __builtin_amdgcn_exp2f(-z * LOG2E);
                out[(size_t)(b0 + bb) * E_ + e] =
                    __builtin_amdgcn_rcpf(1.0f + ezn);
            }
        }
        // next-iter staging writes qt_s/su_s/wt_s (not comb); the
        // stage->__syncthreads() pair also fences comb reuse.
    }
}

extern "C" void kernel_launch(void* const* d_in, const int* in_sizes, int n_in,
                              void* d_out, int out_size, void* d_ws, size_t ws_size,
                              hipStream_t stream) {
    const float* emb_e   = (const float*)d_in[0];
    const float* emb_rel = (const float*)d_in[1];
    const float* nfw     = (const float*)d_in[2];
    const float* lit     = (const float*)d_in[3];
    const float* c       = (const float*)d_in[4];
    const float* var     = (const float*)d_in[5];
    const int*   e1      = (const int*)d_in[6];
    const int*   rel     = (const int*)d_in[7];
    float* out = (float*)d_out;

    char* ws = (char*)d_ws;
    float* qtc = (float*)(ws + QTC_OFF);
    float* suc = (float*)(ws + SUC_OFF);
    float* wtc = (float*)(ws + WTC_OFF);
    float* r   = (float*)(ws + R_OFF);

    setup_k<<<dim3(B_), dim3(256), 0, stream>>>(emb_e, emb_rel, nfw, lit, c, var,
                                                e1, rel, qtc, suc, wtc, r);

    main_k<<<dim3(1880), dim3(256), 0, stream>>>(emb_e, lit, qtc, suc, wtc, r, out);
}

// Round 7
// 71.134 us; speedup vs baseline: 1.6104x; 1.6104x over previous
//
#include <hip/hip_runtime.h>

#define E_ 15000
#define D_ 200
#define L_ 64
#define B_ 256
#define LOG2E 1.4426950408889634f

typedef float v2f __attribute__((ext_vector_type(2)));

// ws layout (chunk-contiguous: chunk c = b's [16c, 16c+16)):
//   qtc @ 0      : [16][200][16] f32  qtc[c][d][bb] = emb_e[e1,d]*emb_rel[rel,d]
//   suc @ 204800 : [16][64][16]  f32  (lit[e1,l]-c[l])*r[l]
//   wtc @ 270336 : [16][64][16]  f32  nfw[rel,l]
//   r   @ 335872 : [64] f32           sqrt(log2e/var[l])
#define QTC_OFF 0
#define SUC_OFF 204800
#define WTC_OFF 270336
#define R_OFF   335872

__global__ __launch_bounds__(256) void setup_k(
    const float* __restrict__ emb_e, const float* __restrict__ emb_rel,
    const float* __restrict__ nfw,   const float* __restrict__ lit,
    const float* __restrict__ c,     const float* __restrict__ var,
    const int* __restrict__ e1,      const int* __restrict__ rel,
    float* __restrict__ qtc, float* __restrict__ suc,
    float* __restrict__ wtc, float* __restrict__ r)
{
    const int b = blockIdx.x;
    const int t = threadIdx.x;
    const int ie = e1[b];
    const int ir = rel[b];
    const int cb = (b >> 4);
    const int bb = (b & 15);
    if (t < D_) qtc[cb * 3200 + t * 16 + bb] =
        emb_e[ie * D_ + t] * emb_rel[ir * D_ + t];
    if (t < L_) {
        const float rl = sqrtf(LOG2E / var[t]);
        suc[cb * 1024 + t * 16 + bb] = (lit[ie * L_ + t] - c[t]) * rl;
        wtc[cb * 1024 + t * 16 + bb] = nfw[ir * L_ + t];
        if (b == 0) r[t] = rl;
    }
}

// 944 blocks = 59 e-tiles x 16 b-chunks; 256 threads, lane -> e (coalesced).
// Per-block: stage this chunk's 21KB of per-b operands into LDS ONCE;
// inner loops read them at wave-uniform addresses (broadcast, conflict-free).
// e-row data (emb_e/lit) streams through float4 global loads exactly once
// per block, as in R1 (proven 80MB fetch). No per-thread arrays -> no spills.
__global__ __launch_bounds__(256) void main_k(
    const float* __restrict__ emb_e, const float* __restrict__ lit,
    const float* __restrict__ qtc,   const float* __restrict__ suc,
    const float* __restrict__ wtc,   const float* __restrict__ r,
    float* __restrict__ out)
{
    __shared__ float qt_s[3200];   // 12.8 KB [d][16]
    __shared__ float su_s[1024];   //  4.0 KB [l][16]
    __shared__ float wt_s[1024];   //  4.0 KB [l][16]
    __shared__ float r_s[64];

    // Bijective XCD swizzle: 944 = 8*118 exact. 118 consecutive orig per XCD
    // = ~7.4 e-tiles (2 MB of emb_e/lit) re-swept 16x from that XCD's L2.
    const int w    = blockIdx.x;
    const int orig = (w & 7) * 118 + (w >> 3);
    const int x = orig >> 4;        // e-tile 0..58
    const int y = orig & 15;        // b-chunk 0..15

    const int tid = threadIdx.x;
    const int e   = x * 256 + tid;
    const int ec  = (e < E_) ? e : (E_ - 1);
    const int b0  = y * 16;

    // ---- one-time coalesced staging: 21 KB L2 -> LDS ----
    {
        const float4* qsrc = (const float4*)qtc + y * 800;
        float4* qdst = (float4*)qt_s;
        #pragma unroll
        for (int i = 0; i < 3; ++i) qdst[tid + 256 * i] = qsrc[tid + 256 * i];
        if (tid < 32) qdst[768 + tid] = qsrc[768 + tid];
        ((float4*)su_s)[tid] = ((const float4*)suc)[y * 256 + tid];
        ((float4*)wt_s)[tid] = ((const float4*)wtc)[y * 256 + tid];
        if (tid < 16) ((float4*)r_s)[tid] = ((const float4*)r)[tid];
    }
    __syncthreads();

    v2f acc[8];
    #pragma unroll
    for (int j = 0; j < 8; ++j) acc[j] = (v2f)(0.0f);

    // ---- structural: acc[bb] += emb_e[ec,d] * qt_s[d][bb] ----
    const float* ep = emb_e + (size_t)ec * D_;   // 16B aligned (200*4B rows)
    #pragma unroll 2
    for (int d = 0; d < D_; d += 4) {
        const float4 v4 = *(const float4*)(ep + d);
        const float va[4] = {v4.x, v4.y, v4.z, v4.w};
        #pragma unroll
        for (int k = 0; k < 4; ++k) {
            const v2f* q2 = (const v2f*)(qt_s + (d + k) * 16);
            const v2f ev = {va[k], va[k]};
            #pragma unroll
            for (int j = 0; j < 8; ++j)
                acc[j] = __builtin_elementwise_fma(ev, q2[j], acc[j]);
        }
    }

    // ---- RBF: acc[bb] += exp2(-(su_s[l][bb] - lit[ec,l]*r[l])^2) * wt_s[l][bb] ----
    const float* lp = lit + (size_t)ec * L_;     // 256B aligned rows
    #pragma unroll 2
    for (int l = 0; l < L_; l += 4) {
        const float4 x4 = *(const float4*)(lp + l);
        const float xa[4] = {x4.x, x4.y, x4.z, x4.w};
        #pragma unroll
        for (int k = 0; k < 4; ++k) {
            const float u = xa[k] * r_s[l + k];
            const v2f uv = {u, u};
            const v2f* s2 = (const v2f*)(su_s + (l + k) * 16);
            const v2f* w2 = (const v2f*)(wt_s + (l + k) * 16);
            #pragma unroll
            for (int j = 0; j < 8; ++j) {
                const v2f t = s2[j] - uv;
                const v2f m = -(t * t);
                const v2f ph = {__builtin_amdgcn_exp2f(m.x),
                                __builtin_amdgcn_exp2f(m.y)};
                acc[j] = __builtin_elementwise_fma(ph, w2[j], acc[j]);
            }
        }
    }

    // ---- sigmoid + coalesced store (1KB contiguous per bb-row) ----
    if (e < E_) {
        #pragma unroll
        for (int j = 0; j < 8; ++j) {
            #pragma unroll
            for (int h = 0; h < 2; ++h) {
                const float z = h ? acc[j].y : acc[j].x;
                const float ezn = __builtin_amdgcn_exp2f(-z * LOG2E);
                out[(size_t)(b0 + 2 * j + h) * E_ + e] =
                    __builtin_amdgcn_rcpf(1.0f + ezn);
            }
        }
    }
}

extern "C" void kernel_launch(void* const* d_in, const int* in_sizes, int n_in,
                              void* d_out, int out_size, void* d_ws, size_t ws_size,
                              hipStream_t stream) {
    const float* emb_e   = (const float*)d_in[0];
    const float* emb_rel = (const float*)d_in[1];
    const float* nfw     = (const float*)d_in[2];
    const float* lit     = (const float*)d_in[3];
    const float* c       = (const float*)d_in[4];
    const float* var     = (const float*)d_in[5];
    const int*   e1      = (const int*)d_in[6];
    const int*   rel     = (const int*)d_in[7];
    float* out = (float*)d_out;

    char* ws = (char*)d_ws;
    float* qtc = (float*)(ws + QTC_OFF);
    float* suc = (float*)(ws + SUC_OFF);
    float* wtc = (float*)(ws + WTC_OFF);
    float* r   = (float*)(ws + R_OFF);

    setup_k<<<dim3(B_), dim3(256), 0, stream>>>(emb_e, emb_rel, nfw, lit, c, var,
                                                e1, rel, qtc, suc, wtc, r);

    main_k<<<dim3(944), dim3(256), 0, stream>>>(emb_e, lit, qtc, suc, wtc, r, out);
}